// Round 2
// baseline (807.516 us; speedup 1.0000x reference)
//
#include <hip/hip_runtime.h>
#include <cstdint>

// SparseMoE on MI355X (gfx950). B=2,S=2048 -> NTOK=4096 tokens, D=1024, E=8,
// H=4096, top_k=2. Sparse grouped-GEMM formulation (non-selected gates are
// exactly 0 in the reference). Dtype-adaptive: a detect kernel classifies the
// input buffers as fp32 or bf16 at runtime; both template variants of each
// dtype-dependent kernel are launched and the wrong one early-exits.

#define DEV __device__ __forceinline__

typedef __attribute__((ext_vector_type(8))) short short8;   // 8 x bf16 (4 VGPRs)
typedef __attribute__((ext_vector_type(4))) float floatx4;  // MFMA accumulator

constexpr int D_ = 1024, E_ = 8, H_ = 4096;
constexpr int NTOK = 4096;          // B*S
constexpr int CAP  = 4096;          // per-expert slot capacity (worst case)
constexpr int TOTSLOT = NTOK * 2;   // top_k=2 -> exactly 8192 slots

// ---- workspace layout (bytes) ----
constexpr size_t O_COUNT = 0;                                   // E ints
constexpr size_t O_FLAG  = 48;                                  // 1 int
constexpr size_t O_OFFS  = 64;                                  // E+1 ints
constexpr size_t O_BTOK  = 128;                                 // E*CAP ints
constexpr size_t O_BGATE = O_BTOK  + (size_t)E_ * CAP * 4;      // E*CAP floats
constexpr size_t O_PAIR  = O_BGATE + (size_t)E_ * CAP * 4;      // NTOK*2 ints
constexpr size_t O_HBUF  = (O_PAIR + (size_t)NTOK * 2 * 4 + 255) & ~(size_t)255;
constexpr size_t O_YBUF  = O_HBUF + (size_t)TOTSLOT * H_ * 2;   // hbuf bf16
constexpr size_t WS_NEED = O_YBUF + (size_t)TOTSLOT * D_ * 2;   // ybuf bf16

DEV float b2f(unsigned short u) {
    union { unsigned int i; float f; } v; v.i = ((unsigned int)u) << 16; return v.f;
}
DEV unsigned int f2b(float f) {  // round-to-nearest-even, returns low 16 bits
    union { float f; unsigned int i; } v; v.f = f;
    unsigned int r = v.i + 0x7fffu + ((v.i >> 16) & 1u);
    return (r >> 16) & 0xffffu;
}

// scalar load of element i as float, DT=0: fp32, DT=1: bf16
template <int DT> DEV float ldf(const void* p, size_t i) {
    if constexpr (DT == 0) return ((const float*)p)[i];
    else return b2f(((const unsigned short*)p)[i]);
}

DEV float gelu_tanh(float x) {
    float u = 0.7978845608028654f * (x + 0.044715f * x * x * x);
    u = fminf(fmaxf(u, -20.f), 20.f);
    float e = __expf(2.f * u);
    float t = (e - 1.f) / (e + 1.f);
    return 0.5f * x * (1.f + t);
}

// ---------------------------------------------------------------------------
// Dtype detect + init. For a bf16 buffer of N(0,1) data, every even-indexed
// ushort is a bf16 normal: exponent field (bits 14:7) in ~[110,130]. For an
// fp32 buffer, the lo ushort of each word is random mantissa bits: exponent
// field uniform over [0,255] -> ~84% outliers. Count outliers over 512 words.
__global__ __launch_bounds__(64) void detect_init(const unsigned int* __restrict__ xw,
                                                  int* flags, int* counts) {
    int lane = threadIdx.x;
    int outl = 0;
    for (int i = lane; i < 512; i += 64) {
        unsigned int lo = xw[i] & 0xffffu;
        unsigned int ef = (lo >> 7) & 0xffu;
        if (ef < 100u || ef > 140u) outl++;
    }
#pragma unroll
    for (int off = 32; off > 0; off >>= 1) outl += __shfl_down(outl, off);
    if (lane == 0) flags[0] = (outl > 64) ? 0 : 1;   // 0 = fp32, 1 = bf16
    if (lane < E_) counts[lane] = 0;
}

// Router: one wave per token, fp64 accumulation (top-k flips vs the np fp32
// ref are the dominant correctness risk; fp64 minimizes our contribution).
template <int DT>
__global__ __launch_bounds__(256) void router_kernel(
    const void* __restrict__ x, const void* __restrict__ noise,
    const void* __restrict__ w_route, const void* __restrict__ b_route,
    const void* __restrict__ w_noise, const void* __restrict__ b_noise,
    void* __restrict__ out,  // gate1 lives at element offset NTOK*D_
    const int* __restrict__ flags, int* counts, int* btok, float* bgate, int* pairs)
{
    if (flags[0] != DT) return;
    int wave = threadIdx.x >> 6, lane = threadIdx.x & 63;
    int t = blockIdx.x * 4 + wave;

    double racc[E_], nacc[E_];
#pragma unroll
    for (int e = 0; e < E_; e++) { racc[e] = 0.0; nacc[e] = 0.0; }

#pragma unroll 4
    for (int i = 0; i < D_ / 64; i++) {
        int j = i * 64 + lane;
        float xv = ldf<DT>(x, (size_t)t * D_ + j);
        float rv[E_], nv[E_];
        if constexpr (DT == 0) {
            const float* wr = (const float*)w_route + (size_t)j * E_;
            const float* wn = (const float*)w_noise + (size_t)j * E_;
            float4 a0 = ((const float4*)wr)[0], a1 = ((const float4*)wr)[1];
            float4 c0 = ((const float4*)wn)[0], c1 = ((const float4*)wn)[1];
            rv[0]=a0.x; rv[1]=a0.y; rv[2]=a0.z; rv[3]=a0.w;
            rv[4]=a1.x; rv[5]=a1.y; rv[6]=a1.z; rv[7]=a1.w;
            nv[0]=c0.x; nv[1]=c0.y; nv[2]=c0.z; nv[3]=c0.w;
            nv[4]=c1.x; nv[5]=c1.y; nv[6]=c1.z; nv[7]=c1.w;
        } else {
            uint4 r8 = *(const uint4*)((const unsigned short*)w_route + (size_t)j * E_);
            uint4 n8 = *(const uint4*)((const unsigned short*)w_noise + (size_t)j * E_);
            const unsigned int rw[4] = {r8.x, r8.y, r8.z, r8.w};
            const unsigned int nw[4] = {n8.x, n8.y, n8.z, n8.w};
#pragma unroll
            for (int p = 0; p < 4; p++) {
                rv[2*p]   = b2f((unsigned short)(rw[p] & 0xffffu));
                rv[2*p+1] = b2f((unsigned short)(rw[p] >> 16));
                nv[2*p]   = b2f((unsigned short)(nw[p] & 0xffffu));
                nv[2*p+1] = b2f((unsigned short)(nw[p] >> 16));
            }
        }
#pragma unroll
        for (int e = 0; e < E_; e++) {
            racc[e] += (double)(xv * rv[e]);
            nacc[e] += (double)(xv * nv[e]);
        }
    }
#pragma unroll
    for (int off = 32; off > 0; off >>= 1)
#pragma unroll
        for (int e = 0; e < E_; e++) {
            racc[e] += __shfl_down(racc[e], off);
            nacc[e] += __shfl_down(nacc[e], off);
        }

    if (lane == 0) {
        double nz[E_];
#pragma unroll
        for (int e = 0; e < E_; e++) {
            double lg = racc[e] + (double)ldf<DT>(b_route, e);
            double nl = nacc[e] + (double)ldf<DT>(b_noise, e);
            double sp = (nl > 0.0) ? nl + log1p(exp(-nl)) : log1p(exp(nl));  // softplus
            nz[e] = lg + (double)ldf<DT>(noise, (size_t)t * E_ + e) * sp;
        }
        double mx = nz[0];
#pragma unroll
        for (int e = 1; e < E_; e++) mx = fmax(mx, nz[e]);
        double se = 0.0, ex[E_];
#pragma unroll
        for (int e = 0; e < E_; e++) { ex[e] = exp(nz[e] - mx); se += ex[e]; }
#pragma unroll
        for (int e = 0; e < E_; e++) {
            float g = (float)(ex[e] / se);
            if constexpr (DT == 0) ((float*)out)[(size_t)NTOK * D_ + (size_t)t * E_ + e] = g;
            else ((unsigned short*)out)[(size_t)NTOK * D_ + (size_t)t * E_ + e] = (unsigned short)f2b(g);
        }
        // top-2 (strict > keeps lower index on ties, matching lax.top_k)
        double v0 = -1e300, v1 = -1e300; int i0 = 0, i1 = 0;
#pragma unroll
        for (int e = 0; e < E_; e++) {
            double v = nz[e];
            if (v > v0) { v1 = v0; i1 = i0; v0 = v; i0 = e; }
            else if (v > v1) { v1 = v; i1 = e; }
        }
        double g0 = 1.0 / (1.0 + exp(v1 - v0));
        float  g1 = (float)(1.0 - g0);
        int l0 = atomicAdd(&counts[i0], 1);
        int l1 = atomicAdd(&counts[i1], 1);
        btok[i0 * CAP + l0] = t;  bgate[i0 * CAP + l0] = (float)g0;
        btok[i1 * CAP + l1] = t;  bgate[i1 * CAP + l1] = g1;
        pairs[2 * t]     = (i0 << 16) | l0;
        pairs[2 * t + 1] = (i1 << 16) | l1;
    }
}

__global__ __launch_bounds__(64) void offsets_kernel(const int* counts, int* offs) {
    if (threadIdx.x == 0) {
        int a = 0;
        for (int e = 0; e < E_; e++) { offs[e] = a; a += counts[e]; }
        offs[E_] = a;
    }
}

// Grouped GEMM: C[128 tokens x 128 n] per block, 4 waves (2x2 of 64x64),
// 16x16x32 bf16 MFMA, BK=64. Weights [K][N] row-major are transposed into LDS
// [n][k] during staging (register repack) so fragment reads are ds_read_b128.
// Global operands (A source for FC, weights, bias) are in DT; hbuf/ybuf bf16.
template <int KD, int ND, bool FC, int DT>
__global__ __launch_bounds__(256) void moe_gemm(
    const void* __restrict__ asrc,        // FC: x [NTOK][KD] (DT); else hbuf bf16
    const void* __restrict__ w,           // [E][KD][ND] (DT)
    const void* __restrict__ bias,        // [E][ND] (DT)
    unsigned short* __restrict__ dst,     // FC: hbuf; else ybuf (bf16)
    const int* __restrict__ flags, const int* __restrict__ counts,
    const int* __restrict__ offs, const int* __restrict__ btok,
    const float* __restrict__ bgate)
{
    if (flags[0] != DT) return;
    const int e = blockIdx.z;
    const int cnt = counts[e];
    const int m0 = blockIdx.y * 128;
    if (m0 >= cnt) return;                 // worst-case grid, early-exit
    const int n0 = blockIdx.x * 128;
    const int off = offs[e];

    __shared__ unsigned short As[128][72];  // [token_row][k]
    __shared__ unsigned short Bs[128][72];  // [n][k]

    const int tid = threadIdx.x;
    const int ar = tid >> 1, ah = tid & 1;          // A: 2 thr/row, 32 elems each
    int am = m0 + ar; if (am > cnt - 1) am = cnt - 1;
    const size_t arow = FC ? (size_t)btok[e * CAP + am] * KD
                           : (size_t)(off + am) * KD;
    const int bn = (tid & 31) * 4;                  // B: 4 n-cols x 8 k-rows
    const int bk = (tid >> 5) * 8;

    const int waveid = tid >> 6, lane = tid & 63;
    const int wm = (waveid & 1) * 64, wn = (waveid >> 1) * 64;
    const int lrow = lane & 15, quad = lane >> 4;

    floatx4 acc[4][4];
#pragma unroll
    for (int fm = 0; fm < 4; fm++)
#pragma unroll
        for (int fn = 0; fn < 4; fn++) acc[fm][fn] = (floatx4)0.f;

    for (int k0 = 0; k0 < KD; k0 += 64) {
        __syncthreads();
        {   // stage A
            uint4* ad = (uint4*)&As[ar][ah * 32];
            if constexpr (FC && DT == 0) {
                const float* ag = (const float*)asrc + arow + k0 + ah * 32;
#pragma unroll
                for (int i = 0; i < 4; i++) {
                    float4 a0 = ((const float4*)ag)[2 * i];
                    float4 a1 = ((const float4*)ag)[2 * i + 1];
                    uint4 pk;
                    pk.x = f2b(a0.x) | (f2b(a0.y) << 16);
                    pk.y = f2b(a0.z) | (f2b(a0.w) << 16);
                    pk.z = f2b(a1.x) | (f2b(a1.y) << 16);
                    pk.w = f2b(a1.z) | (f2b(a1.w) << 16);
                    ad[i] = pk;
                }
            } else {
                const uint4* ag = (const uint4*)((const unsigned short*)asrc + arow + k0 + ah * 32);
#pragma unroll
                for (int i = 0; i < 4; i++) ad[i] = ag[i];
            }
        }
        {   // stage B with transpose
            unsigned short breg[4][8];
#pragma unroll
            for (int j = 0; j < 8; j++) {
                if constexpr (DT == 0) {
                    const float* wp = (const float*)w + (size_t)e * KD * ND
                                      + (size_t)(k0 + bk + j) * ND + n0 + bn;
                    float4 v = *(const float4*)wp;
                    breg[0][j] = (unsigned short)f2b(v.x);
                    breg[1][j] = (unsigned short)f2b(v.y);
                    breg[2][j] = (unsigned short)f2b(v.z);
                    breg[3][j] = (unsigned short)f2b(v.w);
                } else {
                    const unsigned short* wp = (const unsigned short*)w + (size_t)e * KD * ND
                                               + (size_t)(k0 + bk + j) * ND + n0 + bn;
                    uint2 v = *(const uint2*)wp;
                    breg[0][j] = (unsigned short)(v.x & 0xffffu);
                    breg[1][j] = (unsigned short)(v.x >> 16);
                    breg[2][j] = (unsigned short)(v.y & 0xffffu);
                    breg[3][j] = (unsigned short)(v.y >> 16);
                }
            }
#pragma unroll
            for (int c = 0; c < 4; c++) {
                uint4 pk;
                pk.x = (unsigned int)breg[c][0] | ((unsigned int)breg[c][1] << 16);
                pk.y = (unsigned int)breg[c][2] | ((unsigned int)breg[c][3] << 16);
                pk.z = (unsigned int)breg[c][4] | ((unsigned int)breg[c][5] << 16);
                pk.w = (unsigned int)breg[c][6] | ((unsigned int)breg[c][7] << 16);
                *(uint4*)&Bs[bn + c][bk] = pk;
            }
        }
        __syncthreads();
#pragma unroll
        for (int ks = 0; ks < 2; ks++) {
            short8 af[4], bfr[4];
#pragma unroll
            for (int f = 0; f < 4; f++) {
                af[f]  = *(const short8*)&As[wm + f * 16 + lrow][ks * 32 + quad * 8];
                bfr[f] = *(const short8*)&Bs[wn + f * 16 + lrow][ks * 32 + quad * 8];
            }
#pragma unroll
            for (int fm = 0; fm < 4; fm++)
#pragma unroll
                for (int fn = 0; fn < 4; fn++)
                    acc[fm][fn] = __builtin_amdgcn_mfma_f32_16x16x32_bf16(
                        af[fm], bfr[fn], acc[fm][fn], 0, 0, 0);
        }
    }

    // Epilogue. C/D layout: col = lane&15, row = quad*4 + reg.
    const int gc = n0 + wn + lrow;
    float bcol[4];
#pragma unroll
    for (int fn = 0; fn < 4; fn++) bcol[fn] = ldf<DT>(bias, (size_t)e * ND + gc + fn * 16);

#pragma unroll
    for (int fm = 0; fm < 4; fm++) {
        int srow0 = m0 + wm + fm * 16 + quad * 4;
#pragma unroll
        for (int r = 0; r < 4; r++) {
            int srow = srow0 + r;
            if (srow < cnt) {
                size_t base = (size_t)(off + srow) * ND;
                if (FC) {
#pragma unroll
                    for (int fn = 0; fn < 4; fn++) {
                        float v = acc[fm][fn][r] + bcol[fn];
                        dst[base + gc + fn * 16] = (unsigned short)f2b(gelu_tanh(v));
                    }
                } else {
                    float g = bgate[e * CAP + srow];
#pragma unroll
                    for (int fn = 0; fn < 4; fn++) {
                        float v = (acc[fm][fn][r] + bcol[fn]) * g;
                        dst[base + gc + fn * 16] = (unsigned short)f2b(v);
                    }
                }
            }
        }
    }
}

// out[t] = ybuf[slot0(t)] + ybuf[slot1(t)]   (gates already applied)
template <int DT>
__global__ __launch_bounds__(256) void combine_kernel(
    const unsigned short* __restrict__ ybuf, const int* __restrict__ pairs,
    const int* __restrict__ offs, const int* __restrict__ flags, void* __restrict__ out)
{
    if (flags[0] != DT) return;
    int t = blockIdx.x;
    int p0 = pairs[2 * t], p1 = pairs[2 * t + 1];
    size_t r0 = (size_t)(offs[p0 >> 16] + (p0 & 0xffff)) * D_;
    size_t r1 = (size_t)(offs[p1 >> 16] + (p1 & 0xffff)) * D_;
    int c = threadIdx.x * 4;
    uint2 a = *(const uint2*)(ybuf + r0 + c);
    uint2 b = *(const uint2*)(ybuf + r1 + c);
    float s0 = b2f((unsigned short)(a.x & 0xffffu)) + b2f((unsigned short)(b.x & 0xffffu));
    float s1 = b2f((unsigned short)(a.x >> 16))     + b2f((unsigned short)(b.x >> 16));
    float s2 = b2f((unsigned short)(a.y & 0xffffu)) + b2f((unsigned short)(b.y & 0xffffu));
    float s3 = b2f((unsigned short)(a.y >> 16))     + b2f((unsigned short)(b.y >> 16));
    if constexpr (DT == 0) {
        float4 o; o.x = s0; o.y = s1; o.z = s2; o.w = s3;
        *(float4*)((float*)out + (size_t)t * D_ + c) = o;
    } else {
        uint2 o;
        o.x = f2b(s0) | (f2b(s1) << 16);
        o.y = f2b(s2) | (f2b(s3) << 16);
        *(uint2*)((unsigned short*)out + (size_t)t * D_ + c) = o;
    }
}

// ---------------------------------------------------------------------------
extern "C" void kernel_launch(void* const* d_in, const int* in_sizes, int n_in,
                              void* d_out, int out_size, void* d_ws, size_t ws_size,
                              hipStream_t stream) {
    if (ws_size < WS_NEED) return;  // diagnostic: output stays 0 -> absmax == max|ref|

    const void* x       = d_in[0];
    const void* noise   = d_in[1];
    const void* w_route = d_in[2];
    const void* b_route = d_in[3];
    const void* w_noise = d_in[4];
    const void* b_noise = d_in[5];
    const void* w_fc    = d_in[6];
    const void* b_fc    = d_in[7];
    const void* w_proj  = d_in[8];
    const void* b_proj  = d_in[9];
    // d_in[10] = top_k (int32, ==2): baked into the structure.

    char* ws = (char*)d_ws;
    int*   counts = (int*)(ws + O_COUNT);
    int*   flags  = (int*)(ws + O_FLAG);
    int*   offs   = (int*)(ws + O_OFFS);
    int*   btok   = (int*)(ws + O_BTOK);
    float* bgate  = (float*)(ws + O_BGATE);
    int*   pairs  = (int*)(ws + O_PAIR);
    unsigned short* hbuf = (unsigned short*)(ws + O_HBUF);
    unsigned short* ybuf = (unsigned short*)(ws + O_YBUF);

    detect_init<<<dim3(1), dim3(64), 0, stream>>>((const unsigned int*)x, flags, counts);

    router_kernel<0><<<dim3(NTOK / 4), dim3(256), 0, stream>>>(
        x, noise, w_route, b_route, w_noise, b_noise, d_out, flags, counts, btok, bgate, pairs);
    router_kernel<1><<<dim3(NTOK / 4), dim3(256), 0, stream>>>(
        x, noise, w_route, b_route, w_noise, b_noise, d_out, flags, counts, btok, bgate, pairs);

    offsets_kernel<<<dim3(1), dim3(64), 0, stream>>>(counts, offs);

    moe_gemm<D_, H_, true, 0><<<dim3(H_ / 128, 32, E_), dim3(256), 0, stream>>>(
        x, w_fc, b_fc, hbuf, flags, counts, offs, btok, bgate);
    moe_gemm<D_, H_, true, 1><<<dim3(H_ / 128, 32, E_), dim3(256), 0, stream>>>(
        x, w_fc, b_fc, hbuf, flags, counts, offs, btok, bgate);

    moe_gemm<H_, D_, false, 0><<<dim3(D_ / 128, 32, E_), dim3(256), 0, stream>>>(
        hbuf, w_proj, b_proj, ybuf, flags, counts, offs, btok, bgate);
    moe_gemm<H_, D_, false, 1><<<dim3(D_ / 128, 32, E_), dim3(256), 0, stream>>>(
        hbuf, w_proj, b_proj, ybuf, flags, counts, offs, btok, bgate);

    combine_kernel<0><<<dim3(NTOK), dim3(256), 0, stream>>>(ybuf, pairs, offs, flags, d_out);
    combine_kernel<1><<<dim3(NTOK), dim3(256), 0, stream>>>(ybuf, pairs, offs, flags, d_out);
}

// Round 3
// 751.023 us; speedup vs baseline: 1.0752x; 1.0752x over previous
//
#include <hip/hip_runtime.h>
#include <cstdint>

// SparseMoE on MI355X (gfx950). B=2,S=2048 -> NTOK=4096 tokens, D=1024, E=8,
// H=4096, top_k=2. Sparse grouped-GEMM formulation. Dtype-adaptive (fp32 vs
// bf16 inputs) via runtime detect + dual-template launches with early-exit.
// Plan A (ws >= ~161 MB): pre-convert/transpose weights to bf16 [E][N][K],
//   m97-style GEMM (global_load_lds 16B, unpadded LDS, XOR k-group swizzle).
// Plan B (ws >= ~81 MB): round-2 proven register-staging GEMM (fallback).

#define DEV __device__ __forceinline__

typedef __attribute__((ext_vector_type(8))) short short8;   // 8 x bf16
typedef __attribute__((ext_vector_type(4))) float floatx4;  // MFMA accumulator

constexpr int D_ = 1024, E_ = 8, H_ = 4096;
constexpr int NTOK = 4096;
constexpr int CAP  = 4096;
constexpr int TOTSLOT = NTOK * 2;

// ---- workspace layout (bytes) ----
constexpr size_t O_COUNT = 0;
constexpr size_t O_FLAG  = 48;
constexpr size_t O_OFFS  = 64;
constexpr size_t O_BTOK  = 128;
constexpr size_t O_BGATE = O_BTOK  + (size_t)E_ * CAP * 4;
constexpr size_t O_PAIR  = O_BGATE + (size_t)E_ * CAP * 4;
constexpr size_t O_BFC32 = (O_PAIR + (size_t)NTOK * 2 * 4 + 255) & ~(size_t)255;
constexpr size_t O_BPJ32 = O_BFC32 + (size_t)E_ * H_ * 4;
constexpr size_t O_BIG   = (O_BPJ32 + (size_t)E_ * D_ * 4 + 255) & ~(size_t)255;
// Plan A
constexpr size_t O_XG   = O_BIG;                              // 16 MB bf16
constexpr size_t O_HBUF = O_XG   + (size_t)TOTSLOT * D_ * 2;  // 64 MB bf16
constexpr size_t O_YBUF = O_HBUF + (size_t)TOTSLOT * H_ * 2;  // 16 MB bf16
constexpr size_t O_WT   = O_YBUF + (size_t)TOTSLOT * D_ * 2;  // 64 MB bf16 (reused fc->proj)
constexpr size_t WS_A   = O_WT   + (size_t)E_ * D_ * H_ * 2;
// Plan B (round-2 structure)
constexpr size_t OB_HBUF = O_BIG;
constexpr size_t OB_YBUF = OB_HBUF + (size_t)TOTSLOT * H_ * 2;
constexpr size_t WS_B    = OB_YBUF + (size_t)TOTSLOT * D_ * 2;

DEV float b2f(unsigned short u) {
    union { unsigned int i; float f; } v; v.i = ((unsigned int)u) << 16; return v.f;
}
DEV unsigned int f2b(float f) {  // round-to-nearest-even, low 16 bits
    union { float f; unsigned int i; } v; v.f = f;
    unsigned int r = v.i + 0x7fffu + ((v.i >> 16) & 1u);
    return (r >> 16) & 0xffffu;
}
template <int DT> DEV float ldf(const void* p, size_t i) {
    if constexpr (DT == 0) return ((const float*)p)[i];
    else return b2f(((const unsigned short*)p)[i]);
}
DEV float gelu_tanh(float x) {
    float u = 0.7978845608028654f * (x + 0.044715f * x * x * x);
    u = fminf(fmaxf(u, -20.f), 20.f);
    float e = __expf(2.f * u);
    float t = (e - 1.f) / (e + 1.f);
    return 0.5f * x * (1.f + t);
}

// async global->LDS, 16 B per lane. LDS dest = wave-uniform base + lane*16.
// AS(3) pointer from generic via 32-bit truncation (LDS aperture has zero low
// 32 bits on gfx9+; addrspacecast generic->local is exactly this truncate).
typedef __attribute__((address_space(3))) unsigned int lds_u32_t;
typedef const __attribute__((address_space(1))) unsigned int g_u32_t;
DEV void gload16(const unsigned short* g, const unsigned short* l) {
    __builtin_amdgcn_global_load_lds((g_u32_t*)(size_t)g,
                                     (lds_u32_t*)(unsigned int)(size_t)l, 16, 0, 0);
}

// ---------------------------------------------------------------------------
__global__ __launch_bounds__(64) void detect_init(const unsigned int* __restrict__ xw,
                                                  int* flags, int* counts) {
    int lane = threadIdx.x;
    int outl = 0;
    for (int i = lane; i < 512; i += 64) {
        unsigned int lo = xw[i] & 0xffffu;
        unsigned int ef = (lo >> 7) & 0xffu;
        if (ef < 100u || ef > 140u) outl++;
    }
#pragma unroll
    for (int off = 32; off > 0; off >>= 1) outl += __shfl_down(outl, off);
    if (lane == 0) flags[0] = (outl > 64) ? 0 : 1;   // 0 = fp32, 1 = bf16
    if (lane < E_) counts[lane] = 0;
}

// Router: one wave per token, fp64 accumulation (top-k flip minimization).
template <int DT>
__global__ __launch_bounds__(256) void router_kernel(
    const void* __restrict__ x, const void* __restrict__ noise,
    const void* __restrict__ w_route, const void* __restrict__ b_route,
    const void* __restrict__ w_noise, const void* __restrict__ b_noise,
    void* __restrict__ out, const int* __restrict__ flags,
    int* counts, int* btok, float* bgate, int* pairs)
{
    if (flags[0] != DT) return;
    int wave = threadIdx.x >> 6, lane = threadIdx.x & 63;
    int t = blockIdx.x * 4 + wave;

    double racc[E_], nacc[E_];
#pragma unroll
    for (int e = 0; e < E_; e++) { racc[e] = 0.0; nacc[e] = 0.0; }

#pragma unroll 4
    for (int i = 0; i < D_ / 64; i++) {
        int j = i * 64 + lane;
        float xv = ldf<DT>(x, (size_t)t * D_ + j);
        float rv[E_], nv[E_];
        if constexpr (DT == 0) {
            const float* wr = (const float*)w_route + (size_t)j * E_;
            const float* wn = (const float*)w_noise + (size_t)j * E_;
            float4 a0 = ((const float4*)wr)[0], a1 = ((const float4*)wr)[1];
            float4 c0 = ((const float4*)wn)[0], c1 = ((const float4*)wn)[1];
            rv[0]=a0.x; rv[1]=a0.y; rv[2]=a0.z; rv[3]=a0.w;
            rv[4]=a1.x; rv[5]=a1.y; rv[6]=a1.z; rv[7]=a1.w;
            nv[0]=c0.x; nv[1]=c0.y; nv[2]=c0.z; nv[3]=c0.w;
            nv[4]=c1.x; nv[5]=c1.y; nv[6]=c1.z; nv[7]=c1.w;
        } else {
            uint4 r8 = *(const uint4*)((const unsigned short*)w_route + (size_t)j * E_);
            uint4 n8 = *(const uint4*)((const unsigned short*)w_noise + (size_t)j * E_);
            const unsigned int rw[4] = {r8.x, r8.y, r8.z, r8.w};
            const unsigned int nw[4] = {n8.x, n8.y, n8.z, n8.w};
#pragma unroll
            for (int p = 0; p < 4; p++) {
                rv[2*p]   = b2f((unsigned short)(rw[p] & 0xffffu));
                rv[2*p+1] = b2f((unsigned short)(rw[p] >> 16));
                nv[2*p]   = b2f((unsigned short)(nw[p] & 0xffffu));
                nv[2*p+1] = b2f((unsigned short)(nw[p] >> 16));
            }
        }
#pragma unroll
        for (int e = 0; e < E_; e++) {
            racc[e] += (double)(xv * rv[e]);
            nacc[e] += (double)(xv * nv[e]);
        }
    }
#pragma unroll
    for (int off = 32; off > 0; off >>= 1)
#pragma unroll
        for (int e = 0; e < E_; e++) {
            racc[e] += __shfl_down(racc[e], off);
            nacc[e] += __shfl_down(nacc[e], off);
        }

    if (lane == 0) {
        double nz[E_];
#pragma unroll
        for (int e = 0; e < E_; e++) {
            double lg = racc[e] + (double)ldf<DT>(b_route, e);
            double nl = nacc[e] + (double)ldf<DT>(b_noise, e);
            double sp = (nl > 0.0) ? nl + log1p(exp(-nl)) : log1p(exp(nl));
            nz[e] = lg + (double)ldf<DT>(noise, (size_t)t * E_ + e) * sp;
        }
        double mx = nz[0];
#pragma unroll
        for (int e = 1; e < E_; e++) mx = fmax(mx, nz[e]);
        double se = 0.0, ex[E_];
#pragma unroll
        for (int e = 0; e < E_; e++) { ex[e] = exp(nz[e] - mx); se += ex[e]; }
#pragma unroll
        for (int e = 0; e < E_; e++) {
            float g = (float)(ex[e] / se);
            if constexpr (DT == 0) ((float*)out)[(size_t)NTOK * D_ + (size_t)t * E_ + e] = g;
            else ((unsigned short*)out)[(size_t)NTOK * D_ + (size_t)t * E_ + e] = (unsigned short)f2b(g);
        }
        double v0 = -1e300, v1 = -1e300; int i0 = 0, i1 = 0;
#pragma unroll
        for (int e = 0; e < E_; e++) {
            double v = nz[e];
            if (v > v0) { v1 = v0; i1 = i0; v0 = v; i0 = e; }
            else if (v > v1) { v1 = v; i1 = e; }
        }
        double g0 = 1.0 / (1.0 + exp(v1 - v0));
        float  g1 = (float)(1.0 - g0);
        int l0 = atomicAdd(&counts[i0], 1);
        int l1 = atomicAdd(&counts[i1], 1);
        btok[i0 * CAP + l0] = t;  bgate[i0 * CAP + l0] = (float)g0;
        btok[i1 * CAP + l1] = t;  bgate[i1 * CAP + l1] = g1;
        pairs[2 * t]     = (i0 << 16) | l0;
        pairs[2 * t + 1] = (i1 << 16) | l1;
    }
}

__global__ __launch_bounds__(64) void offsets_kernel(const int* counts, int* offs) {
    if (threadIdx.x == 0) {
        int a = 0;
        for (int e = 0; e < E_; e++) { offs[e] = a; a += counts[e]; }
        offs[E_] = a;
    }
}

// ---- Plan A preprocessing -------------------------------------------------
// biases -> fp32 scratch so the GEMM is dtype-free
template <int DT>
__global__ __launch_bounds__(256) void conv_bias(
    const void* __restrict__ b_fc, const void* __restrict__ b_proj,
    const int* __restrict__ flags, float* __restrict__ bfc32, float* __restrict__ bpj32)
{
    if (flags[0] != DT) return;
    int i = blockIdx.x * 256 + threadIdx.x;
    if (i < E_ * H_) bfc32[i] = ldf<DT>(b_fc, i);
    if (i < E_ * D_) bpj32[i] = ldf<DT>(b_proj, i);
}

// gather x rows into bucket order as bf16: xg[offs[e]+i] = bf16(x[btok[e][i]])
template <int DT>
__global__ __launch_bounds__(256) void gather_x(
    const void* __restrict__ x, const int* __restrict__ btok,
    const int* __restrict__ counts, const int* __restrict__ offs,
    const int* __restrict__ flags, unsigned short* __restrict__ xg)
{
    if (flags[0] != DT) return;
    int e = blockIdx.y, i = blockIdx.x;
    if (i >= counts[e]) return;
    int t = btok[e * CAP + i];
    size_t src = (size_t)t * D_;
    size_t dst = (size_t)(offs[e] + i) * D_;
    int c = threadIdx.x * 4;
    if constexpr (DT == 0) {
        float4 v = *(const float4*)((const float*)x + src + c);
        uint2 o;
        o.x = f2b(v.x) | (f2b(v.y) << 16);
        o.y = f2b(v.z) | (f2b(v.w) << 16);
        *(uint2*)(xg + dst + c) = o;
    } else {
        *(uint2*)(xg + dst + c) = *(const uint2*)((const unsigned short*)x + src + c);
    }
}

// transpose+convert: w [E][K][N] (DT) -> wT [E][N][K] bf16. 64x64 LDS tiles.
template <int DT>
__global__ __launch_bounds__(256) void transpose_w(
    const void* __restrict__ w, unsigned short* __restrict__ wT,
    const int* __restrict__ flags, int K, int N)
{
    if (flags[0] != DT) return;
    __shared__ unsigned short t[64][65];
    const int e  = blockIdx.z;
    const int k0 = blockIdx.y * 64;
    const int n0 = blockIdx.x * 64;
    const int r  = threadIdx.x >> 2;          // 0..63
    const int c4 = (threadIdx.x & 3) * 16;    // 0,16,32,48
    if constexpr (DT == 0) {
        const float* src = (const float*)w + ((size_t)e * K + k0 + r) * N + n0 + c4;
#pragma unroll
        for (int i = 0; i < 4; i++) {
            float4 v = ((const float4*)src)[i];
            t[r][c4 + 4*i + 0] = (unsigned short)f2b(v.x);
            t[r][c4 + 4*i + 1] = (unsigned short)f2b(v.y);
            t[r][c4 + 4*i + 2] = (unsigned short)f2b(v.z);
            t[r][c4 + 4*i + 3] = (unsigned short)f2b(v.w);
        }
    } else {
        const unsigned short* src = (const unsigned short*)w + ((size_t)e * K + k0 + r) * N + n0 + c4;
#pragma unroll
        for (int i = 0; i < 2; i++) {
            uint4 v = ((const uint4*)src)[i];
            const unsigned int wds[4] = {v.x, v.y, v.z, v.w};
#pragma unroll
            for (int p = 0; p < 4; p++) {
                t[r][c4 + 8*i + 2*p]     = (unsigned short)(wds[p] & 0xffffu);
                t[r][c4 + 8*i + 2*p + 1] = (unsigned short)(wds[p] >> 16);
            }
        }
    }
    __syncthreads();
    unsigned short* dstp = wT + ((size_t)e * N + n0 + r) * K + k0 + c4;
    unsigned short tmp[16];
#pragma unroll
    for (int i = 0; i < 16; i++) tmp[i] = t[c4 + i][r];
#pragma unroll
    for (int h = 0; h < 2; h++) {
        uint4 pk;
        pk.x = (unsigned int)tmp[8*h+0] | ((unsigned int)tmp[8*h+1] << 16);
        pk.y = (unsigned int)tmp[8*h+2] | ((unsigned int)tmp[8*h+3] << 16);
        pk.z = (unsigned int)tmp[8*h+4] | ((unsigned int)tmp[8*h+5] << 16);
        pk.w = (unsigned int)tmp[8*h+6] | ((unsigned int)tmp[8*h+7] << 16);
        ((uint4*)dstp)[h] = pk;
    }
}

// ---- Plan A GEMM: m97 structure -------------------------------------------
// 128x128 tile, 4 waves (2x2 of 64x64), 16x16x32 bf16 MFMA, BK=64.
// Both operands bf16 K-contiguous; staged via global_load_lds width=16 into
// unpadded LDS [row][64] with XOR k-group swizzle (kills same-bank reads):
//   LDS[row][g*8..] holds global k-group (g ^ (row&7)).
template <int KD, int ND, bool FC>
__global__ __launch_bounds__(256) void moe_gemm2(
    const unsigned short* __restrict__ A,    // [TOTSLOT][KD] bf16 (xg or hbuf)
    const unsigned short* __restrict__ wT,   // [E][ND][KD] bf16
    const float* __restrict__ bias32,        // [E][ND] fp32
    unsigned short* __restrict__ dst,        // [TOTSLOT][ND] bf16
    const int* __restrict__ counts, const int* __restrict__ offs,
    const float* __restrict__ bgate)
{
    const int e = blockIdx.z;
    const int cnt = counts[e];
    const int m0 = blockIdx.y * 128;
    if (m0 >= cnt) return;
    const int n0 = blockIdx.x * 128;
    const int off = offs[e];

    __shared__ unsigned short As[128 * 64];
    __shared__ unsigned short Bs[128 * 64];

    const int tid = threadIdx.x;
    const int waveid = tid >> 6, lane = tid & 63;
    const int sr = lane >> 3;            // row within 8-row chunk
    const int g  = lane & 7;             // k-group slot in LDS
    const int scol = ((g ^ sr) * 8);     // swizzled global k-offset (elems)

    // per-lane global row pointers for this wave's 4 A-chunks / 4 B-chunks
    const unsigned short* aAddr[4];
    const unsigned short* bAddr[4];
#pragma unroll
    for (int c = 0; c < 4; c++) {
        int ar = m0 + (waveid * 4 + c) * 8 + sr;
        if (ar > cnt - 1) ar = cnt - 1;
        aAddr[c] = A + (size_t)(off + ar) * KD + scol;
        int br = n0 + (waveid * 4 + c) * 8 + sr;
        bAddr[c] = wT + ((size_t)e * ND + br) * KD + scol;
    }
    const int ldsChunk = (waveid * 4) * 512;   // elems; +512 per chunk

    const int wm = (waveid & 1) * 64, wn = (waveid >> 1) * 64;
    const int lrow = lane & 15, quad = lane >> 4;

    floatx4 acc[4][4];
#pragma unroll
    for (int fm = 0; fm < 4; fm++)
#pragma unroll
        for (int fn = 0; fn < 4; fn++) acc[fm][fn] = (floatx4)0.f;

    for (int k0 = 0; k0 < KD; k0 += 64) {
        __syncthreads();   // all waves done reading previous tile
#pragma unroll
        for (int c = 0; c < 4; c++) {
            gload16(aAddr[c] + k0, &As[ldsChunk + c * 512]);
            gload16(bAddr[c] + k0, &Bs[ldsChunk + c * 512]);
        }
        __syncthreads();   // drains vmcnt -> staging visible
#pragma unroll
        for (int ks = 0; ks < 2; ks++) {
            short8 af[4], bfr[4];
#pragma unroll
            for (int f = 0; f < 4; f++) {
                int Ra = wm + f * 16 + lrow;
                int Rb = wn + f * 16 + lrow;
                af[f]  = *(const short8*)&As[Ra * 64 + ((ks * 4 + quad) ^ (Ra & 7)) * 8];
                bfr[f] = *(const short8*)&Bs[Rb * 64 + ((ks * 4 + quad) ^ (Rb & 7)) * 8];
            }
#pragma unroll
            for (int fm = 0; fm < 4; fm++)
#pragma unroll
                for (int fn = 0; fn < 4; fn++)
                    acc[fm][fn] = __builtin_amdgcn_mfma_f32_16x16x32_bf16(
                        af[fm], bfr[fn], acc[fm][fn], 0, 0, 0);
        }
    }

    // Epilogue. C/D layout: col = lane&15, row = quad*4 + reg.
    const int gc = n0 + wn + lrow;
    float bcol[4];
#pragma unroll
    for (int fn = 0; fn < 4; fn++) bcol[fn] = bias32[(size_t)e * ND + gc + fn * 16];

#pragma unroll
    for (int fm = 0; fm < 4; fm++) {
        int srow0 = m0 + wm + fm * 16 + quad * 4;
#pragma unroll
        for (int r = 0; r < 4; r++) {
            int srow = srow0 + r;
            if (srow < cnt) {
                size_t base = (size_t)(off + srow) * ND;
                if (FC) {
#pragma unroll
                    for (int fn = 0; fn < 4; fn++) {
                        float v = acc[fm][fn][r] + bcol[fn];
                        dst[base + gc + fn * 16] = (unsigned short)f2b(gelu_tanh(v));
                    }
                } else {
                    float gt = bgate[e * CAP + srow];
#pragma unroll
                    for (int fn = 0; fn < 4; fn++) {
                        float v = (acc[fm][fn][r] + bcol[fn]) * gt;
                        dst[base + gc + fn * 16] = (unsigned short)f2b(v);
                    }
                }
            }
        }
    }
}

// ---- Plan B GEMM (round-2 proven fallback) --------------------------------
template <int KD, int ND, bool FC, int DT>
__global__ __launch_bounds__(256) void moe_gemm(
    const void* __restrict__ asrc, const void* __restrict__ w,
    const void* __restrict__ bias, unsigned short* __restrict__ dst,
    const int* __restrict__ flags, const int* __restrict__ counts,
    const int* __restrict__ offs, const int* __restrict__ btok,
    const float* __restrict__ bgate)
{
    if (flags[0] != DT) return;
    const int e = blockIdx.z;
    const int cnt = counts[e];
    const int m0 = blockIdx.y * 128;
    if (m0 >= cnt) return;
    const int n0 = blockIdx.x * 128;
    const int off = offs[e];

    __shared__ unsigned short As[128][72];
    __shared__ unsigned short Bs[128][72];

    const int tid = threadIdx.x;
    const int ar = tid >> 1, ah = tid & 1;
    int am = m0 + ar; if (am > cnt - 1) am = cnt - 1;
    const size_t arow = FC ? (size_t)btok[e * CAP + am] * KD
                           : (size_t)(off + am) * KD;
    const int bn = (tid & 31) * 4;
    const int bk = (tid >> 5) * 8;

    const int waveid = tid >> 6, lane = tid & 63;
    const int wm = (waveid & 1) * 64, wn = (waveid >> 1) * 64;
    const int lrow = lane & 15, quad = lane >> 4;

    floatx4 acc[4][4];
#pragma unroll
    for (int fm = 0; fm < 4; fm++)
#pragma unroll
        for (int fn = 0; fn < 4; fn++) acc[fm][fn] = (floatx4)0.f;

    for (int k0 = 0; k0 < KD; k0 += 64) {
        __syncthreads();
        {
            uint4* ad = (uint4*)&As[ar][ah * 32];
            if constexpr (FC && DT == 0) {
                const float* ag = (const float*)asrc + arow + k0 + ah * 32;
#pragma unroll
                for (int i = 0; i < 4; i++) {
                    float4 a0 = ((const float4*)ag)[2 * i];
                    float4 a1 = ((const float4*)ag)[2 * i + 1];
                    uint4 pk;
                    pk.x = f2b(a0.x) | (f2b(a0.y) << 16);
                    pk.y = f2b(a0.z) | (f2b(a0.w) << 16);
                    pk.z = f2b(a1.x) | (f2b(a1.y) << 16);
                    pk.w = f2b(a1.z) | (f2b(a1.w) << 16);
                    ad[i] = pk;
                }
            } else {
                const uint4* ag = (const uint4*)((const unsigned short*)asrc + arow + k0 + ah * 32);
#pragma unroll
                for (int i = 0; i < 4; i++) ad[i] = ag[i];
            }
        }
        {
            unsigned short breg[4][8];
#pragma unroll
            for (int j = 0; j < 8; j++) {
                if constexpr (DT == 0) {
                    const float* wp = (const float*)w + (size_t)e * KD * ND
                                      + (size_t)(k0 + bk + j) * ND + n0 + bn;
                    float4 v = *(const float4*)wp;
                    breg[0][j] = (unsigned short)f2b(v.x);
                    breg[1][j] = (unsigned short)f2b(v.y);
                    breg[2][j] = (unsigned short)f2b(v.z);
                    breg[3][j] = (unsigned short)f2b(v.w);
                } else {
                    const unsigned short* wp = (const unsigned short*)w + (size_t)e * KD * ND
                                               + (size_t)(k0 + bk + j) * ND + n0 + bn;
                    uint2 v = *(const uint2*)wp;
                    breg[0][j] = (unsigned short)(v.x & 0xffffu);
                    breg[1][j] = (unsigned short)(v.x >> 16);
                    breg[2][j] = (unsigned short)(v.y & 0xffffu);
                    breg[3][j] = (unsigned short)(v.y >> 16);
                }
            }
#pragma unroll
            for (int c = 0; c < 4; c++) {
                uint4 pk;
                pk.x = (unsigned int)breg[c][0] | ((unsigned int)breg[c][1] << 16);
                pk.y = (unsigned int)breg[c][2] | ((unsigned int)breg[c][3] << 16);
                pk.z = (unsigned int)breg[c][4] | ((unsigned int)breg[c][5] << 16);
                pk.w = (unsigned int)breg[c][6] | ((unsigned int)breg[c][7] << 16);
                *(uint4*)&Bs[bn + c][bk] = pk;
            }
        }
        __syncthreads();
#pragma unroll
        for (int ks = 0; ks < 2; ks++) {
            short8 af[4], bfr[4];
#pragma unroll
            for (int f = 0; f < 4; f++) {
                af[f]  = *(const short8*)&As[wm + f * 16 + lrow][ks * 32 + quad * 8];
                bfr[f] = *(const short8*)&Bs[wn + f * 16 + lrow][ks * 32 + quad * 8];
            }
#pragma unroll
            for (int fm = 0; fm < 4; fm++)
#pragma unroll
                for (int fn = 0; fn < 4; fn++)
                    acc[fm][fn] = __builtin_amdgcn_mfma_f32_16x16x32_bf16(
                        af[fm], bfr[fn], acc[fm][fn], 0, 0, 0);
        }
    }

    const int gc = n0 + wn + lrow;
    float bcol[4];
#pragma unroll
    for (int fn = 0; fn < 4; fn++) bcol[fn] = ldf<DT>(bias, (size_t)e * ND + gc + fn * 16);

#pragma unroll
    for (int fm = 0; fm < 4; fm++) {
        int srow0 = m0 + wm + fm * 16 + quad * 4;
#pragma unroll
        for (int r = 0; r < 4; r++) {
            int srow = srow0 + r;
            if (srow < cnt) {
                size_t base = (size_t)(off + srow) * ND;
                if (FC) {
#pragma unroll
                    for (int fn = 0; fn < 4; fn++) {
                        float v = acc[fm][fn][r] + bcol[fn];
                        dst[base + gc + fn * 16] = (unsigned short)f2b(gelu_tanh(v));
                    }
                } else {
                    float g = bgate[e * CAP + srow];
#pragma unroll
                    for (int fn = 0; fn < 4; fn++) {
                        float v = (acc[fm][fn][r] + bcol[fn]) * g;
                        dst[base + gc + fn * 16] = (unsigned short)f2b(v);
                    }
                }
            }
        }
    }
}

// out[t] = ybuf[slot0(t)] + ybuf[slot1(t)]
template <int DT>
__global__ __launch_bounds__(256) void combine_kernel(
    const unsigned short* __restrict__ ybuf, const int* __restrict__ pairs,
    const int* __restrict__ offs, const int* __restrict__ flags, void* __restrict__ out)
{
    if (flags[0] != DT) return;
    int t = blockIdx.x;
    int p0 = pairs[2 * t], p1 = pairs[2 * t + 1];
    size_t r0 = (size_t)(offs[p0 >> 16] + (p0 & 0xffff)) * D_;
    size_t r1 = (size_t)(offs[p1 >> 16] + (p1 & 0xffff)) * D_;
    int c = threadIdx.x * 4;
    uint2 a = *(const uint2*)(ybuf + r0 + c);
    uint2 b = *(const uint2*)(ybuf + r1 + c);
    float s0 = b2f((unsigned short)(a.x & 0xffffu)) + b2f((unsigned short)(b.x & 0xffffu));
    float s1 = b2f((unsigned short)(a.x >> 16))     + b2f((unsigned short)(b.x >> 16));
    float s2 = b2f((unsigned short)(a.y & 0xffffu)) + b2f((unsigned short)(b.y & 0xffffu));
    float s3 = b2f((unsigned short)(a.y >> 16))     + b2f((unsigned short)(b.y >> 16));
    if constexpr (DT == 0) {
        float4 o; o.x = s0; o.y = s1; o.z = s2; o.w = s3;
        *(float4*)((float*)out + (size_t)t * D_ + c) = o;
    } else {
        uint2 o;
        o.x = f2b(s0) | (f2b(s1) << 16);
        o.y = f2b(s2) | (f2b(s3) << 16);
        *(uint2*)((unsigned short*)out + (size_t)t * D_ + c) = o;
    }
}

// ---------------------------------------------------------------------------
extern "C" void kernel_launch(void* const* d_in, const int* in_sizes, int n_in,
                              void* d_out, int out_size, void* d_ws, size_t ws_size,
                              hipStream_t stream) {
    if (ws_size < WS_B) return;  // diagnostic: output stays 0

    const void* x       = d_in[0];
    const void* noise   = d_in[1];
    const void* w_route = d_in[2];
    const void* b_route = d_in[3];
    const void* w_noise = d_in[4];
    const void* b_noise = d_in[5];
    const void* w_fc    = d_in[6];
    const void* b_fc    = d_in[7];
    const void* w_proj  = d_in[8];
    const void* b_proj  = d_in[9];

    char* ws = (char*)d_ws;
    int*   counts = (int*)(ws + O_COUNT);
    int*   flags  = (int*)(ws + O_FLAG);
    int*   offs   = (int*)(ws + O_OFFS);
    int*   btok   = (int*)(ws + O_BTOK);
    float* bgate  = (float*)(ws + O_BGATE);
    int*   pairs  = (int*)(ws + O_PAIR);

    detect_init<<<dim3(1), dim3(64), 0, stream>>>((const unsigned int*)x, flags, counts);
    router_kernel<0><<<dim3(NTOK / 4), dim3(256), 0, stream>>>(
        x, noise, w_route, b_route, w_noise, b_noise, d_out, flags, counts, btok, bgate, pairs);
    router_kernel<1><<<dim3(NTOK / 4), dim3(256), 0, stream>>>(
        x, noise, w_route, b_route, w_noise, b_noise, d_out, flags, counts, btok, bgate, pairs);
    offsets_kernel<<<dim3(1), dim3(64), 0, stream>>>(counts, offs);

    if (ws_size >= WS_A) {
        // ---- Plan A ----
        float* bfc32 = (float*)(ws + O_BFC32);
        float* bpj32 = (float*)(ws + O_BPJ32);
        unsigned short* xg   = (unsigned short*)(ws + O_XG);
        unsigned short* hbuf = (unsigned short*)(ws + O_HBUF);
        unsigned short* ybuf = (unsigned short*)(ws + O_YBUF);
        unsigned short* wT   = (unsigned short*)(ws + O_WT);

        conv_bias<0><<<dim3((E_ * H_ + 255) / 256), dim3(256), 0, stream>>>(b_fc, b_proj, flags, bfc32, bpj32);
        conv_bias<1><<<dim3((E_ * H_ + 255) / 256), dim3(256), 0, stream>>>(b_fc, b_proj, flags, bfc32, bpj32);
        gather_x<0><<<dim3(CAP, E_), dim3(256), 0, stream>>>(x, btok, counts, offs, flags, xg);
        gather_x<1><<<dim3(CAP, E_), dim3(256), 0, stream>>>(x, btok, counts, offs, flags, xg);

        // FC: w_fc [E][D][H] -> wT [E][H][D]
        transpose_w<0><<<dim3(H_ / 64, D_ / 64, E_), dim3(256), 0, stream>>>(w_fc, wT, flags, D_, H_);
        transpose_w<1><<<dim3(H_ / 64, D_ / 64, E_), dim3(256), 0, stream>>>(w_fc, wT, flags, D_, H_);
        moe_gemm2<D_, H_, true><<<dim3(H_ / 128, 32, E_), dim3(256), 0, stream>>>(
            xg, wT, bfc32, hbuf, counts, offs, bgate);

        // proj: w_proj [E][H][D] -> wT [E][D][H] (reuses wT buffer)
        transpose_w<0><<<dim3(D_ / 64, H_ / 64, E_), dim3(256), 0, stream>>>(w_proj, wT, flags, H_, D_);
        transpose_w<1><<<dim3(D_ / 64, H_ / 64, E_), dim3(256), 0, stream>>>(w_proj, wT, flags, H_, D_);
        moe_gemm2<H_, D_, false><<<dim3(D_ / 128, 32, E_), dim3(256), 0, stream>>>(
            hbuf, wT, bpj32, ybuf, counts, offs, bgate);

        combine_kernel<0><<<dim3(NTOK), dim3(256), 0, stream>>>(ybuf, pairs, offs, flags, d_out);
        combine_kernel<1><<<dim3(NTOK), dim3(256), 0, stream>>>(ybuf, pairs, offs, flags, d_out);
    } else {
        // ---- Plan B (round-2 proven path) ----
        unsigned short* hbuf = (unsigned short*)(ws + OB_HBUF);
        unsigned short* ybuf = (unsigned short*)(ws + OB_YBUF);

        moe_gemm<D_, H_, true, 0><<<dim3(H_ / 128, 32, E_), dim3(256), 0, stream>>>(
            x, w_fc, b_fc, hbuf, flags, counts, offs, btok, bgate);
        moe_gemm<D_, H_, true, 1><<<dim3(H_ / 128, 32, E_), dim3(256), 0, stream>>>(
            x, w_fc, b_fc, hbuf, flags, counts, offs, btok, bgate);
        moe_gemm<H_, D_, false, 0><<<dim3(D_ / 128, 32, E_), dim3(256), 0, stream>>>(
            hbuf, w_proj, b_proj, ybuf, flags, counts, offs, btok, bgate);
        moe_gemm<H_, D_, false, 1><<<dim3(D_ / 128, 32, E_), dim3(256), 0, stream>>>(
            hbuf, w_proj, b_proj, ybuf, flags, counts, offs, btok, bgate);

        combine_kernel<0><<<dim3(NTOK), dim3(256), 0, stream>>>(ybuf, pairs, offs, flags, d_out);
        combine_kernel<1><<<dim3(NTOK), dim3(256), 0, stream>>>(ybuf, pairs, offs, flags, d_out);
    }
}

// Round 4
// 716.591 us; speedup vs baseline: 1.1269x; 1.0481x over previous
//
#include <hip/hip_runtime.h>
#include <cstdint>

// SparseMoE on MI355X (gfx950). fp32 inputs (proven R1/R2: bf16 interp NaN'd,
// fp32 passed). B=2,S=2048 -> NTOK=4096 tokens, D=1024, E=8, H=4096, top_k=2.
// Sparse grouped-GEMM: pre-transpose weights to bf16 [E][N][K], m97-style GEMM
// (global_load_lds 16B, XOR k-swizzle, 0 bank conflicts measured), XCD-aware
// 1-D block mapping so each XCD's L2 keeps a resident B-slice (R3 showed the
// GEMMs are cache-traffic-bound: dur ~= tile-bytes / 6.3 TB/s).

#define DEV __device__ __forceinline__

typedef __attribute__((ext_vector_type(8))) short short8;   // 8 x bf16
typedef __attribute__((ext_vector_type(4))) float floatx4;  // MFMA accumulator

constexpr int D_ = 1024, E_ = 8, H_ = 4096;
constexpr int NTOK = 4096;
constexpr int CAP  = 4096;
constexpr int TOTSLOT = NTOK * 2;

// ---- workspace layout (bytes); ~160.3 MB, proven available in R3 ----
constexpr size_t O_COUNT = 0;
constexpr size_t O_OFFS  = 64;
constexpr size_t O_BTOK  = 128;
constexpr size_t O_BGATE = O_BTOK  + (size_t)E_ * CAP * 4;
constexpr size_t O_PAIR  = O_BGATE + (size_t)E_ * CAP * 4;
constexpr size_t O_XG    = (O_PAIR + (size_t)NTOK * 2 * 4 + 255) & ~(size_t)255;
constexpr size_t O_HBUF  = O_XG   + (size_t)TOTSLOT * D_ * 2;  // 16 MB
constexpr size_t O_YBUF  = O_HBUF + (size_t)TOTSLOT * H_ * 2;  // 64 MB
constexpr size_t O_WT    = O_YBUF + (size_t)TOTSLOT * D_ * 2;  // 16 MB
constexpr size_t WS_NEED = O_WT   + (size_t)E_ * D_ * H_ * 2;  // + 64 MB

DEV float b2f(unsigned short u) {
    union { unsigned int i; float f; } v; v.i = ((unsigned int)u) << 16; return v.f;
}
DEV unsigned int f2b(float f) {  // round-to-nearest-even, low 16 bits
    union { float f; unsigned int i; } v; v.f = f;
    unsigned int r = v.i + 0x7fffu + ((v.i >> 16) & 1u);
    return (r >> 16) & 0xffffu;
}
DEV float gelu_tanh(float x) {
    float u = 0.7978845608028654f * (x + 0.044715f * x * x * x);
    u = fminf(fmaxf(u, -20.f), 20.f);
    float e = __expf(2.f * u);
    float t = (e - 1.f) / (e + 1.f);
    return 0.5f * x * (1.f + t);
}

// async global->LDS, 16 B per lane (dest = wave-uniform base + lane*16)
typedef __attribute__((address_space(3))) unsigned int lds_u32_t;
typedef const __attribute__((address_space(1))) unsigned int g_u32_t;
DEV void gload16(const unsigned short* g, const unsigned short* l) {
    __builtin_amdgcn_global_load_lds((g_u32_t*)(size_t)g,
                                     (lds_u32_t*)(unsigned int)(size_t)l, 16, 0, 0);
}

// ---------------------------------------------------------------------------
__global__ __launch_bounds__(64) void zero_counts(int* counts) {
    if (threadIdx.x < E_) counts[threadIdx.x] = 0;
}

// Router: one wave per token, fp64 accumulation (minimizes top-k flips vs the
// np fp32 reference — the dominant correctness risk; proven R2/R3).
__global__ __launch_bounds__(256) void router_kernel(
    const float* __restrict__ x, const float* __restrict__ noise,
    const float* __restrict__ w_route, const float* __restrict__ b_route,
    const float* __restrict__ w_noise, const float* __restrict__ b_noise,
    float* __restrict__ out,  // gate1 at element offset NTOK*D_
    int* counts, int* btok, float* bgate, int* pairs)
{
    int wave = threadIdx.x >> 6, lane = threadIdx.x & 63;
    int t = blockIdx.x * 4 + wave;

    double racc[E_], nacc[E_];
#pragma unroll
    for (int e = 0; e < E_; e++) { racc[e] = 0.0; nacc[e] = 0.0; }

#pragma unroll 4
    for (int i = 0; i < D_ / 64; i++) {
        int j = i * 64 + lane;
        float xv = x[(size_t)t * D_ + j];
        const float* wr = w_route + (size_t)j * E_;
        const float* wn = w_noise + (size_t)j * E_;
        float4 a0 = ((const float4*)wr)[0], a1 = ((const float4*)wr)[1];
        float4 c0 = ((const float4*)wn)[0], c1 = ((const float4*)wn)[1];
        const float rv[8] = {a0.x,a0.y,a0.z,a0.w,a1.x,a1.y,a1.z,a1.w};
        const float nv[8] = {c0.x,c0.y,c0.z,c0.w,c1.x,c1.y,c1.z,c1.w};
#pragma unroll
        for (int e = 0; e < E_; e++) {
            racc[e] += (double)(xv * rv[e]);
            nacc[e] += (double)(xv * nv[e]);
        }
    }
#pragma unroll
    for (int off = 32; off > 0; off >>= 1)
#pragma unroll
        for (int e = 0; e < E_; e++) {
            racc[e] += __shfl_down(racc[e], off);
            nacc[e] += __shfl_down(nacc[e], off);
        }

    if (lane == 0) {
        double nz[E_];
#pragma unroll
        for (int e = 0; e < E_; e++) {
            double lg = racc[e] + (double)b_route[e];
            double nl = nacc[e] + (double)b_noise[e];
            double sp = (nl > 0.0) ? nl + log1p(exp(-nl)) : log1p(exp(nl));
            nz[e] = lg + (double)noise[(size_t)t * E_ + e] * sp;
        }
        double mx = nz[0];
#pragma unroll
        for (int e = 1; e < E_; e++) mx = fmax(mx, nz[e]);
        double se = 0.0, ex[E_];
#pragma unroll
        for (int e = 0; e < E_; e++) { ex[e] = exp(nz[e] - mx); se += ex[e]; }
#pragma unroll
        for (int e = 0; e < E_; e++)
            out[(size_t)NTOK * D_ + (size_t)t * E_ + e] = (float)(ex[e] / se);
        // top-2 (strict > keeps lower index on ties, matching lax.top_k)
        double v0 = -1e300, v1 = -1e300; int i0 = 0, i1 = 0;
#pragma unroll
        for (int e = 0; e < E_; e++) {
            double v = nz[e];
            if (v > v0) { v1 = v0; i1 = i0; v0 = v; i0 = e; }
            else if (v > v1) { v1 = v; i1 = e; }
        }
        double g0 = 1.0 / (1.0 + exp(v1 - v0));
        float  g1 = (float)(1.0 - g0);
        int l0 = atomicAdd(&counts[i0], 1);
        int l1 = atomicAdd(&counts[i1], 1);
        btok[i0 * CAP + l0] = t;  bgate[i0 * CAP + l0] = (float)g0;
        btok[i1 * CAP + l1] = t;  bgate[i1 * CAP + l1] = g1;
        pairs[2 * t]     = (i0 << 16) | l0;
        pairs[2 * t + 1] = (i1 << 16) | l1;
    }
}

__global__ __launch_bounds__(64) void offsets_kernel(const int* counts, int* offs) {
    if (threadIdx.x == 0) {
        int a = 0;
        for (int e = 0; e < E_; e++) { offs[e] = a; a += counts[e]; }
        offs[E_] = a;
    }
}

// Scatter x rows (fp32 -> bf16) to both selected slots. One block per token:
// x read exactly once, coalesced; no dead blocks.
__global__ __launch_bounds__(256) void gather_x(
    const float* __restrict__ x, const int* __restrict__ pairs,
    const int* __restrict__ offs, unsigned short* __restrict__ xg)
{
    int t = blockIdx.x;
    int c = threadIdx.x * 4;
    float4 v = *(const float4*)(x + (size_t)t * D_ + c);
    uint2 o;
    o.x = f2b(v.x) | (f2b(v.y) << 16);
    o.y = f2b(v.z) | (f2b(v.w) << 16);
    int p0 = pairs[2 * t], p1 = pairs[2 * t + 1];
    size_t r0 = (size_t)(offs[p0 >> 16] + (p0 & 0xffff)) * D_;
    size_t r1 = (size_t)(offs[p1 >> 16] + (p1 & 0xffff)) * D_;
    *(uint2*)(xg + r0 + c) = o;
    *(uint2*)(xg + r1 + c) = o;
}

// transpose+convert: w [E][K][N] fp32 -> wT [E][N][K] bf16. 64x64 LDS tiles.
__global__ __launch_bounds__(256) void transpose_w(
    const float* __restrict__ w, unsigned short* __restrict__ wT, int K, int N)
{
    __shared__ unsigned short t[64][65];
    const int e  = blockIdx.z;
    const int k0 = blockIdx.y * 64;
    const int n0 = blockIdx.x * 64;
    const int r  = threadIdx.x >> 2;          // 0..63
    const int c4 = (threadIdx.x & 3) * 16;    // 0,16,32,48
    const float* src = w + ((size_t)e * K + k0 + r) * N + n0 + c4;
#pragma unroll
    for (int i = 0; i < 4; i++) {
        float4 v = ((const float4*)src)[i];
        t[r][c4 + 4*i + 0] = (unsigned short)f2b(v.x);
        t[r][c4 + 4*i + 1] = (unsigned short)f2b(v.y);
        t[r][c4 + 4*i + 2] = (unsigned short)f2b(v.z);
        t[r][c4 + 4*i + 3] = (unsigned short)f2b(v.w);
    }
    __syncthreads();
    unsigned short* dstp = wT + ((size_t)e * N + n0 + r) * K + k0 + c4;
    unsigned short tmp[16];
#pragma unroll
    for (int i = 0; i < 16; i++) tmp[i] = t[c4 + i][r];
#pragma unroll
    for (int h = 0; h < 2; h++) {
        uint4 pk;
        pk.x = (unsigned int)tmp[8*h+0] | ((unsigned int)tmp[8*h+1] << 16);
        pk.y = (unsigned int)tmp[8*h+2] | ((unsigned int)tmp[8*h+3] << 16);
        pk.z = (unsigned int)tmp[8*h+4] | ((unsigned int)tmp[8*h+5] << 16);
        pk.w = (unsigned int)tmp[8*h+6] | ((unsigned int)tmp[8*h+7] << 16);
        ((uint4*)dstp)[h] = pk;
    }
}

// ---- grouped GEMM, m97 structure + XCD-aware 1-D mapping -------------------
// 128x128 tile, 4 waves (2x2 of 64x64), 16x16x32 bf16 MFMA, BK=64.
// Block -> XCD is lin%8 (m09); we give each XCD a fixed n-slice so its 4 MB L2
// keeps the B-slice resident (FC: 4 n-tiles = 1 MB; proj: 1 n-tile = 1 MB) and
// (FC) iterates nsub fastest so the A-tile is L2-reused across its 4 n-tiles.
template <int KD, int ND, bool FC>
__global__ __launch_bounds__(256) void moe_gemm3(
    const unsigned short* __restrict__ A,    // [TOTSLOT][KD] bf16 (xg or hbuf)
    const unsigned short* __restrict__ wT,   // [E][ND][KD] bf16
    const float* __restrict__ bias32,        // [E][ND] fp32 (direct input)
    unsigned short* __restrict__ dst,        // [TOTSLOT][ND] bf16
    const int* __restrict__ counts, const int* __restrict__ offs,
    const float* __restrict__ bgate)
{
    const int lin = blockIdx.x;
    const int xcd = lin & 7, slot = lin >> 3;
    int e, mt, nt;
    if (FC) {            // ND=4096: 32 n-tiles, 4 per XCD, nsub fastest
        nt = xcd * 4 + (slot & 3);
        mt = (slot >> 2) & 31;
        e  = slot >> 7;
    } else {             // ND=1024: 8 n-tiles, 1 per XCD, m fastest
        nt = xcd;
        mt = slot & 31;
        e  = slot >> 5;
    }
    const int cnt = counts[e];
    const int m0 = mt * 128;
    if (m0 >= cnt) return;
    const int n0 = nt * 128;
    const int off = offs[e];

    __shared__ unsigned short As[128 * 64];
    __shared__ unsigned short Bs[128 * 64];

    const int tid = threadIdx.x;
    const int waveid = tid >> 6, lane = tid & 63;
    const int sr = lane >> 3;            // row within 8-row chunk
    const int g  = lane & 7;             // k-group slot in LDS
    const int scol = ((g ^ sr) * 8);     // XOR-swizzled global k-offset

    const unsigned short* aAddr[4];
    const unsigned short* bAddr[4];
#pragma unroll
    for (int c = 0; c < 4; c++) {
        int ar = m0 + (waveid * 4 + c) * 8 + sr;
        if (ar > cnt - 1) ar = cnt - 1;
        aAddr[c] = A + (size_t)(off + ar) * KD + scol;
        int br = n0 + (waveid * 4 + c) * 8 + sr;
        bAddr[c] = wT + ((size_t)e * ND + br) * KD + scol;
    }
    const int ldsChunk = (waveid * 4) * 512;

    const int wm = (waveid & 1) * 64, wn = (waveid >> 1) * 64;
    const int lrow = lane & 15, quad = lane >> 4;

    floatx4 acc[4][4];
#pragma unroll
    for (int fm = 0; fm < 4; fm++)
#pragma unroll
        for (int fn = 0; fn < 4; fn++) acc[fm][fn] = (floatx4)0.f;

    for (int k0 = 0; k0 < KD; k0 += 64) {
        __syncthreads();
#pragma unroll
        for (int c = 0; c < 4; c++) {
            gload16(aAddr[c] + k0, &As[ldsChunk + c * 512]);
            gload16(bAddr[c] + k0, &Bs[ldsChunk + c * 512]);
        }
        __syncthreads();
#pragma unroll
        for (int ks = 0; ks < 2; ks++) {
            short8 af[4], bfr[4];
#pragma unroll
            for (int f = 0; f < 4; f++) {
                int Ra = wm + f * 16 + lrow;
                int Rb = wn + f * 16 + lrow;
                af[f]  = *(const short8*)&As[Ra * 64 + ((ks * 4 + quad) ^ (Ra & 7)) * 8];
                bfr[f] = *(const short8*)&Bs[Rb * 64 + ((ks * 4 + quad) ^ (Rb & 7)) * 8];
            }
#pragma unroll
            for (int fm = 0; fm < 4; fm++)
#pragma unroll
                for (int fn = 0; fn < 4; fn++)
                    acc[fm][fn] = __builtin_amdgcn_mfma_f32_16x16x32_bf16(
                        af[fm], bfr[fn], acc[fm][fn], 0, 0, 0);
        }
    }

    // Epilogue. C/D layout: col = lane&15, row = quad*4 + reg.
    const int gc = n0 + wn + lrow;
    float bcol[4];
#pragma unroll
    for (int fn = 0; fn < 4; fn++) bcol[fn] = bias32[(size_t)e * ND + gc + fn * 16];

#pragma unroll
    for (int fm = 0; fm < 4; fm++) {
        int srow0 = m0 + wm + fm * 16 + quad * 4;
#pragma unroll
        for (int r = 0; r < 4; r++) {
            int srow = srow0 + r;
            if (srow < cnt) {
                size_t base = (size_t)(off + srow) * ND;
                if (FC) {
#pragma unroll
                    for (int fn = 0; fn < 4; fn++) {
                        float v = acc[fm][fn][r] + bcol[fn];
                        dst[base + gc + fn * 16] = (unsigned short)f2b(gelu_tanh(v));
                    }
                } else {
                    float gt = bgate[e * CAP + srow];
#pragma unroll
                    for (int fn = 0; fn < 4; fn++) {
                        float v = (acc[fm][fn][r] + bcol[fn]) * gt;
                        dst[base + gc + fn * 16] = (unsigned short)f2b(v);
                    }
                }
            }
        }
    }
}

// out[t] = ybuf[slot0(t)] + ybuf[slot1(t)]  (gates already applied), fp32 out
__global__ __launch_bounds__(256) void combine_kernel(
    const unsigned short* __restrict__ ybuf, const int* __restrict__ pairs,
    const int* __restrict__ offs, float* __restrict__ out)
{
    int t = blockIdx.x;
    int p0 = pairs[2 * t], p1 = pairs[2 * t + 1];
    size_t r0 = (size_t)(offs[p0 >> 16] + (p0 & 0xffff)) * D_;
    size_t r1 = (size_t)(offs[p1 >> 16] + (p1 & 0xffff)) * D_;
    int c = threadIdx.x * 4;
    uint2 a = *(const uint2*)(ybuf + r0 + c);
    uint2 b = *(const uint2*)(ybuf + r1 + c);
    float4 o;
    o.x = b2f((unsigned short)(a.x & 0xffffu)) + b2f((unsigned short)(b.x & 0xffffu));
    o.y = b2f((unsigned short)(a.x >> 16))     + b2f((unsigned short)(b.x >> 16));
    o.z = b2f((unsigned short)(a.y & 0xffffu)) + b2f((unsigned short)(b.y & 0xffffu));
    o.w = b2f((unsigned short)(a.y >> 16))     + b2f((unsigned short)(b.y >> 16));
    *(float4*)(out + (size_t)t * D_ + c) = o;
}

// ---------------------------------------------------------------------------
extern "C" void kernel_launch(void* const* d_in, const int* in_sizes, int n_in,
                              void* d_out, int out_size, void* d_ws, size_t ws_size,
                              hipStream_t stream) {
    if (ws_size < WS_NEED) return;  // diagnostic: output stays 0

    const float* x       = (const float*)d_in[0];
    const float* noise   = (const float*)d_in[1];
    const float* w_route = (const float*)d_in[2];
    const float* b_route = (const float*)d_in[3];
    const float* w_noise = (const float*)d_in[4];
    const float* b_noise = (const float*)d_in[5];
    const float* w_fc    = (const float*)d_in[6];
    const float* b_fc    = (const float*)d_in[7];
    const float* w_proj  = (const float*)d_in[8];
    const float* b_proj  = (const float*)d_in[9];

    char* ws = (char*)d_ws;
    int*   counts = (int*)(ws + O_COUNT);
    int*   offs   = (int*)(ws + O_OFFS);
    int*   btok   = (int*)(ws + O_BTOK);
    float* bgate  = (float*)(ws + O_BGATE);
    int*   pairs  = (int*)(ws + O_PAIR);
    unsigned short* xg   = (unsigned short*)(ws + O_XG);
    unsigned short* hbuf = (unsigned short*)(ws + O_HBUF);
    unsigned short* ybuf = (unsigned short*)(ws + O_YBUF);
    unsigned short* wT   = (unsigned short*)(ws + O_WT);

    zero_counts<<<dim3(1), dim3(64), 0, stream>>>(counts);
    router_kernel<<<dim3(NTOK / 4), dim3(256), 0, stream>>>(
        x, noise, w_route, b_route, w_noise, b_noise, (float*)d_out,
        counts, btok, bgate, pairs);
    offsets_kernel<<<dim3(1), dim3(64), 0, stream>>>(counts, offs);
    gather_x<<<dim3(NTOK), dim3(256), 0, stream>>>(x, pairs, offs, xg);

    // FC: w_fc [E][D][H] -> wT [E][H][D]
    transpose_w<<<dim3(H_ / 64, D_ / 64, E_), dim3(256), 0, stream>>>(w_fc, wT, D_, H_);
    moe_gemm3<D_, H_, true><<<dim3(8 * 32 * 32), dim3(256), 0, stream>>>(
        xg, wT, b_fc, hbuf, counts, offs, bgate);

    // proj: w_proj [E][H][D] -> wT [E][D][H]
    transpose_w<<<dim3(D_ / 64, H_ / 64, E_), dim3(256), 0, stream>>>(w_proj, wT, H_, D_);
    moe_gemm3<H_, D_, false><<<dim3(8 * 32 * 8), dim3(256), 0, stream>>>(
        hbuf, wT, b_proj, ybuf, counts, offs, bgate);

    combine_kernel<<<dim3(NTOK), dim3(256), 0, stream>>>(ybuf, pairs, offs, (float*)d_out);
}